// Round 10
// baseline (335.075 us; speedup 1.0000x reference)
//
#include <hip/hip_runtime.h>
#include <stdint.h>

#define BB 1024
#define SS 512
#define HH 128
#define MM 4            // batch rows per block
#define BLK 512         // 8 waves, 1 block/CU, 2 waves/SIMD
#define NBLK (BB / MM)  // 256 blocks -> 1 per CU
#define RS 32           // h-trajectory ring slots (flush every 32 steps)
#define RStr 136        // ring row stride in f16

typedef float f32x4 __attribute__((ext_vector_type(4)));
typedef float f32x2 __attribute__((ext_vector_type(2)));
typedef _Float16 f16x8 __attribute__((ext_vector_type(8)));

#define L2E 1.44269504088896f

__device__ __forceinline__ float rcp_fast(float x)  { return __builtin_amdgcn_rcpf(x); }
__device__ __forceinline__ float exp2_fast(float x) { return __builtin_amdgcn_exp2f(x); }

__global__ __launch_bounds__(BLK, 2) void pig_kernel(
    const float* __restrict__ x0, const float* __restrict__ v_seq,
    const float* __restrict__ W_ih, const float* __restrict__ W_hh,
    const float* __restrict__ b_ih, const float* __restrict__ b_hh,
    const float* __restrict__ W_out, const float* __restrict__ b_out,
    const float* __restrict__ W_r1, const float* __restrict__ b_r1,
    const float* __restrict__ W_r2, const float* __restrict__ b_r2,
    float* __restrict__ out)
{
    // hp2: [parity][kk 0..3][quadk 0..3][m 0..3][8 f16] = 512 f16/parity (1 KB).
    // hp2[kk][qk][m][i] = h[m][kk*32 + qk*8 + i]  (plain f16, no lo row).
    // MFMA A-row mapping: row r holds h[r>>2] (each h-row replicated 4x), so
    // lane (quad,col) reads h[col>>2] and its acc REG 0 = D[4*quad][col] =
    // gh[m=quad][j] -- the lane's own batch row at a COMPILE-TIME reg index.
    // The 9-op hi/lo combine is gone; K-split combine is 3 adds.
    // Bank check: read = 16 unique 16B addrs/instr = 2 words/bank -> 2-way (free);
    // write = 1 ds_write_b16/wave, 2 lanes/word -> 2-way (free).
    __shared__ __align__(16) _Float16 hp2[2][512];          // 2 KB
    __shared__ __align__(16) _Float16 ring[RS * 4 * RStr];  // 34 KB: [slot][m][j]
    __shared__ __align__(16) float    v_lds[SS * 8];        // 16 KB: [t][m*2+o]
    __shared__ __align__(16) float    xs[RS + 1][8];        // x_pred window (+carry at [0])
    __shared__ __align__(16) float    wpk[64][8];           // {W_r1[u][0..3], b_r1[u], W_r2[0][u], W_r2[1][u], 0}
    __shared__ float xc[2][8];                              // x_prev carry, flush-parity buffered

    const int tid  = threadIdx.x;
    const int wave = tid >> 6;
    const int lane = tid & 63;
    const int quad = lane >> 4;         // batch row m for this lane
    const int col  = lane & 15;
    const int row0 = blockIdx.x * MM;
    const int j    = wave * 16 + col;   // this lane's hidden index

    // ---- W_hh B-fragments (f16): wave w owns gates nt*128 + w*16 .. +15 ----
    f16x8 whi[3][4];
#pragma unroll
    for (int nt = 0; nt < 3; ++nt) {
        const int g = nt * HH + j;
#pragma unroll
        for (int kk = 0; kk < 4; ++kk) {
            const float* p = W_hh + g * HH + kk * 32 + quad * 8;
            f16x8 fh;
#pragma unroll
            for (int i = 0; i < 8; ++i) fh[i] = (_Float16)p[i];
            whi[nt][kk] = fh;
        }
    }

    // ---- gate-math per-lane constants (hidden index j, batch row m=quad) ----
    const float wr0 = W_ih[j*2],        wr1 = W_ih[j*2+1];
    const float wz0 = W_ih[(HH+j)*2],   wz1 = W_ih[(HH+j)*2+1];
    const float wn0 = W_ih[(2*HH+j)*2], wn1 = W_ih[(2*HH+j)*2+1];
    const float br  = b_ih[j]      + b_hh[j];
    const float bz  = b_ih[HH+j]   + b_hh[HH+j];
    const float bni = b_ih[2*HH+j];
    const float bnh = b_hh[2*HH+j];

    // ---- hp2 addressing ----
    // read: lane (quad,col) -> data for A-row col = h[col>>2][kk*32+quad*8+i]
    const int rbase = quad * 32 + (col >> 2) * 8;      // f16 units (+kk*128)
    // write: h[m=quad][j]: kk=j>>5, quadk=(j>>3)&3, elem j&7
    const int wbase = (j >> 5) * 128 + ((j >> 3) & 3) * 32 + quad * 8 + (j & 7);

    // ---- pass-A constants: group g8 = tid>>3 -> (o, m, tt8); lane-in-group l8 ----
    const int g8  = tid >> 3;
    const int l8  = tid & 7;
    const int oA  = g8 & 1;
    const int mA  = (g8 >> 1) & 3;
    const int tt8 = g8 >> 3;            // 0..7
    float woA[16];
#pragma unroll
    for (int i = 0; i < 16; ++i) woA[i] = W_out[oA * HH + l8 * 16 + i];
    const float boA = b_out[oA];

    // ---- pass-B constants: (tB, mB, qB) ----
    const int qB = tid & 3;
    const int mB = (tid >> 2) & 3;
    const int tB = tid >> 4;            // 0..31
    const float b2B = b_r2[qB & 1];

    // ---- init ----
    for (int idx = tid; idx < 2 * 512; idx += BLK) ((_Float16*)hp2)[idx] = (_Float16)0.0f;
    for (int idx = tid; idx < MM * SS * 2; idx += BLK) {
        const int m = idx >> 10, i = idx & 1023;          // i = t*2 + o
        v_lds[(i >> 1) * 8 + m * 2 + (i & 1)] = v_seq[(size_t)(row0 + m) * (SS * 2) + i];
    }
    if (tid < 64) {   // packed residual-MLP weights
        wpk[tid][0] = W_r1[tid*4];   wpk[tid][1] = W_r1[tid*4+1];
        wpk[tid][2] = W_r1[tid*4+2]; wpk[tid][3] = W_r1[tid*4+3];
        wpk[tid][4] = b_r1[tid];
        wpk[tid][5] = W_r2[tid];     wpk[tid][6] = W_r2[64 + tid];
        wpk[tid][7] = 0.0f;
    }
    if (tid < 8)
        xc[0][tid] = x0[(size_t)(row0 + (tid >> 1)) * 2 + (tid & 1)];
    __syncthreads();

    float hold = 0.0f;   // h[quad][j] in fp32 — the only recurrent state
    f32x2 vv2 = *(const f32x2*)&v_lds[quad * 2];   // prefetched v[t] (t=0)
    // x-projection terms hoisted off the post-MFMA critical path
    float vxr = vv2[0]*wr0 + vv2[1]*wr1 + br;
    float vxz = vv2[0]*wz0 + vv2[1]*wz1 + bz;
    float vxn = vv2[0]*wn0 + vv2[1]*wn1 + bni;

    for (int t = 0; t < SS; ++t) {
        const int cur = t & 1, nxt = cur ^ 1;

        // ---------- recurrence: 12 MFMA as 6 independent 2-deep chains ----------
        f32x4 aL0 = {0,0,0,0}, aL1 = {0,0,0,0}, aL2 = {0,0,0,0};
        f32x4 aG0 = {0,0,0,0}, aG1 = {0,0,0,0}, aG2 = {0,0,0,0};
        const _Float16* hb = &hp2[cur][rbase];
        {
            f16x8 af0 = *(const f16x8*)&hb[0 * 128];
            f16x8 af1 = *(const f16x8*)&hb[1 * 128];
            f16x8 af2 = *(const f16x8*)&hb[2 * 128];
            f16x8 af3 = *(const f16x8*)&hb[3 * 128];
            aL0 = __builtin_amdgcn_mfma_f32_16x16x32_f16(af0, whi[0][0], aL0, 0, 0, 0);
            aL1 = __builtin_amdgcn_mfma_f32_16x16x32_f16(af0, whi[1][0], aL1, 0, 0, 0);
            aL2 = __builtin_amdgcn_mfma_f32_16x16x32_f16(af0, whi[2][0], aL2, 0, 0, 0);
            aG0 = __builtin_amdgcn_mfma_f32_16x16x32_f16(af2, whi[0][2], aG0, 0, 0, 0);
            aG1 = __builtin_amdgcn_mfma_f32_16x16x32_f16(af2, whi[1][2], aG1, 0, 0, 0);
            aG2 = __builtin_amdgcn_mfma_f32_16x16x32_f16(af2, whi[2][2], aG2, 0, 0, 0);
            aL0 = __builtin_amdgcn_mfma_f32_16x16x32_f16(af1, whi[0][1], aL0, 0, 0, 0);
            aL1 = __builtin_amdgcn_mfma_f32_16x16x32_f16(af1, whi[1][1], aL1, 0, 0, 0);
            aL2 = __builtin_amdgcn_mfma_f32_16x16x32_f16(af1, whi[2][1], aL2, 0, 0, 0);
            aG0 = __builtin_amdgcn_mfma_f32_16x16x32_f16(af3, whi[0][3], aG0, 0, 0, 0);
            aG1 = __builtin_amdgcn_mfma_f32_16x16x32_f16(af3, whi[1][3], aG1, 0, 0, 0);
            aG2 = __builtin_amdgcn_mfma_f32_16x16x32_f16(af3, whi[2][3], aG2, 0, 0, 0);
        }
        // reg 0 = this lane's own batch row (row-replication mapping)
        const float gh0 = aL0[0] + aG0[0];
        const float gh1 = aL1[0] + aG1[0];
        const float gh2 = aL2[0] + aG2[0];

        const float r  = rcp_fast(1.0f + exp2_fast((gh0 + vxr) * (-L2E)));
        const float z  = rcp_fast(1.0f + exp2_fast((gh1 + vxz) * (-L2E)));
        const float na = vxn + r * (gh2 + bnh);
        const float n  = fmaf(2.0f, rcp_fast(1.0f + exp2_fast(na * (-2.0f * L2E))), -1.0f);
        hold = fmaf(z, hold - n, n);

        const _Float16 hh = (_Float16)hold;
        hp2[nxt][wbase] = hh;
        ring[((t & (RS-1)) * 4 + quad) * RStr + j] = hh;   // h_seq[t] for the epilogue

        // prefetch + precompute next step's x-projection (barrier shadow)
        vv2 = *(const f32x2*)&v_lds[((t + 1) & (SS - 1)) * 8 + quad * 2];
        vxr = vv2[0]*wr0 + vv2[1]*wr1 + br;
        vxz = vv2[0]*wz0 + vv2[1]*wz1 + bz;
        vxn = vv2[0]*wn0 + vv2[1]*wn1 + bni;

        __syncthreads();

        // ---------- batched epilogue every RS steps ----------
        if ((t & (RS - 1)) == (RS - 1)) {
            const int f  = t >> 5;       // flush index
            const int t0 = t - (RS - 1);

            // pass A: x_pred for the window (8-lane dot groups, 4 passes)
            if (tid < 8) xs[0][tid] = xc[f & 1][tid];
#pragma unroll
            for (int p = 0; p < 4; ++p) {
                const int tt = p * 8 + tt8;
                const f16x8 h0 = *(const f16x8*)&ring[(tt * 4 + mA) * RStr + l8 * 16];
                const f16x8 h1 = *(const f16x8*)&ring[(tt * 4 + mA) * RStr + l8 * 16 + 8];
                float acc = 0.0f;
#pragma unroll
                for (int i = 0; i < 8; ++i) {
                    acc += (float)h0[i] * woA[i];
                    acc += (float)h1[i] * woA[8 + i];
                }
                acc += __shfl_xor(acc, 1, 64);
                acc += __shfl_xor(acc, 2, 64);
                acc += __shfl_xor(acc, 4, 64);
                if (l8 == 0) xs[1 + tt][mA * 2 + oA] = acc + boA;
            }
            __syncthreads();

            // pass B: residual MLP + violations + stores; thread = (tB, mB, qB)
            // u = uu*4 + qB: the 4 qB lanes read banks {0,8,16,24} -> conflict-free
            {
                const float xp0 = xs[tB][mB*2], xp1 = xs[tB][mB*2+1];
                const f32x2 vt2 = *(const f32x2*)&v_lds[(t0 + tB) * 8 + mB * 2];
                float rss0 = 0.0f, rss1 = 0.0f;
#pragma unroll
                for (int uu = 0; uu < 16; ++uu) {
                    const int u = uu * 4 + qB;
                    const f32x4 wA = *(const f32x4*)&wpk[u][0];
                    const f32x4 wB = *(const f32x4*)&wpk[u][4];
                    const float hu = fmaxf(wB[0] + wA[0]*xp0 + wA[1]*xp1 + wA[2]*vt2[0] + wA[3]*vt2[1], 0.0f);
                    rss0 += hu * wB[1];
                    rss1 += hu * wB[2];
                }
                rss0 += __shfl_xor(rss0, 1, 64);
                rss1 += __shfl_xor(rss1, 1, 64);
                rss0 += __shfl_xor(rss0, 2, 64);
                rss1 += __shfl_xor(rss1, 2, 64);
                if (qB < 2) {
                    const int o = qB;
                    const float xpred = xs[tB + 1][mB*2 + o];
                    const float xpv   = xs[tB][mB*2 + o];
                    const float vv    = v_lds[(t0 + tB) * 8 + mB*2 + o];
                    const float resid = (o ? rss1 : rss0) + b2B;
                    const float viol  = xpred - (xpv + vv + resid);
                    const size_t base = (size_t)(row0 + mB) * (SS * 2) + (t0 + tB) * 2 + o;
                    out[base] = xpred;
                    out[(size_t)BB * SS * 2 + base] = viol;
                }
                if (tid < 8) xc[(f + 1) & 1][tid] = xs[RS][tid];   // carry to next window
            }
            __syncthreads();
        }
    }
}

extern "C" void kernel_launch(void* const* d_in, const int* in_sizes, int n_in,
                              void* d_out, int out_size, void* d_ws, size_t ws_size,
                              hipStream_t stream) {
    pig_kernel<<<dim3(NBLK), dim3(BLK), 0, stream>>>(
        (const float*)d_in[0],  (const float*)d_in[1],  (const float*)d_in[2],
        (const float*)d_in[3],  (const float*)d_in[4],  (const float*)d_in[5],
        (const float*)d_in[6],  (const float*)d_in[7],  (const float*)d_in[8],
        (const float*)d_in[9],  (const float*)d_in[10], (const float*)d_in[11],
        (float*)d_out);
}

// Round 11
// 316.110 us; speedup vs baseline: 1.0600x; 1.0600x over previous
//
#include <hip/hip_runtime.h>
#include <stdint.h>

#define BB 1024
#define SS 512
#define HH 128
#define MM 4            // batch rows per block
#define BLK 512         // 8 waves, 1 block/CU, 2 waves/SIMD
#define NBLK (BB / MM)  // 256 blocks -> 1 per CU
#define RS 32           // h-trajectory ring slots (flush every 32 steps)
#define RStr 136        // ring row stride in f16

typedef float f32x4 __attribute__((ext_vector_type(4)));
typedef float f32x2 __attribute__((ext_vector_type(2)));
typedef _Float16 f16x8 __attribute__((ext_vector_type(8)));

#define L2E 1.44269504088896f

__device__ __forceinline__ float rcp_fast(float x)  { return __builtin_amdgcn_rcpf(x); }
__device__ __forceinline__ float exp2_fast(float x) { return __builtin_amdgcn_exp2f(x); }

__global__ __launch_bounds__(BLK, 2) void pig_kernel(
    const float* __restrict__ x0, const float* __restrict__ v_seq,
    const float* __restrict__ W_ih, const float* __restrict__ W_hh,
    const float* __restrict__ b_ih, const float* __restrict__ b_hh,
    const float* __restrict__ W_out, const float* __restrict__ b_out,
    const float* __restrict__ W_r1, const float* __restrict__ b_r1,
    const float* __restrict__ W_r2, const float* __restrict__ b_r2,
    float* __restrict__ out)
{
    // hp2: [parity][kk 0..3][quadk 0..3][m 0..3][8 f16] = 512 f16/parity (1 KB).
    // A-row r holds h[r>>2] (4x replication) -> lane (quad,col) acc REG 0 =
    // gh[m=quad][j] at a compile-time index.  Gate-chain is software-pipelined
    // at source level: gate-0's 4 MFMA complete first, its exp2 issues (trans
    // pipe) under gate-1's MFMA (matrix pipe), etc.  x-projections are
    // pre-scaled by -L2E / -2L2E in the barrier shadow so each gate's
    // post-MFMA prologue is a single fma.
    __shared__ __align__(16) _Float16 hp2[2][512];          // 2 KB
    __shared__ __align__(16) _Float16 ring[RS * 4 * RStr];  // 34 KB: [slot][m][j]
    __shared__ __align__(16) float    v_lds[SS * 8];        // 16 KB: [t][m*2+o]
    __shared__ __align__(16) float    xs[RS + 1][8];        // x_pred window (+carry at [0])
    __shared__ __align__(16) float    wpk[64][8];           // {W_r1[u][0..3], b_r1[u], W_r2[0][u], W_r2[1][u], 0}
    __shared__ float xc[2][8];                              // x_prev carry, flush-parity buffered

    const int tid  = threadIdx.x;
    const int wave = tid >> 6;
    const int lane = tid & 63;
    const int quad = lane >> 4;         // batch row m for this lane
    const int col  = lane & 15;
    const int row0 = blockIdx.x * MM;
    const int j    = wave * 16 + col;   // this lane's hidden index

    // ---- W_hh B-fragments (f16): wave w owns gates nt*128 + w*16 .. +15 ----
    f16x8 whi[3][4];
#pragma unroll
    for (int nt = 0; nt < 3; ++nt) {
        const int g = nt * HH + j;
#pragma unroll
        for (int kk = 0; kk < 4; ++kk) {
            const float* p = W_hh + g * HH + kk * 32 + quad * 8;
            f16x8 fh;
#pragma unroll
            for (int i = 0; i < 8; ++i) fh[i] = (_Float16)p[i];
            whi[nt][kk] = fh;
        }
    }

    // ---- gate-math per-lane constants, PRE-SCALED for exp2 args ----
    // r,z: arg = -L2E*(gh + vx);  n: arg = -2L2E*(vxn + r*(gh2+bnh))
    const float wr0 = W_ih[j*2]        * (-L2E), wr1 = W_ih[j*2+1]        * (-L2E);
    const float wz0 = W_ih[(HH+j)*2]   * (-L2E), wz1 = W_ih[(HH+j)*2+1]   * (-L2E);
    const float wn0 = W_ih[(2*HH+j)*2] * (-2.0f*L2E), wn1 = W_ih[(2*HH+j)*2+1] * (-2.0f*L2E);
    const float brS  = (b_ih[j]      + b_hh[j])      * (-L2E);
    const float bzS  = (b_ih[HH+j]   + b_hh[HH+j])   * (-L2E);
    const float bniS = b_ih[2*HH+j] * (-2.0f*L2E);
    const float bnhS = b_hh[2*HH+j] * (-2.0f*L2E);   // -2L2E*bnh

    // ---- hp2 addressing ----
    const int rbase = quad * 32 + (col >> 2) * 8;      // read (+kk*128 f16)
    const int wbase = (j >> 5) * 128 + ((j >> 3) & 3) * 32 + quad * 8 + (j & 7);

    // ---- pass-A constants: group g8 = tid>>3 -> (o, m, tt8); lane-in-group l8 ----
    const int g8  = tid >> 3;
    const int l8  = tid & 7;
    const int oA  = g8 & 1;
    const int mA  = (g8 >> 1) & 3;
    const int tt8 = g8 >> 3;            // 0..7
    float woA[16];
#pragma unroll
    for (int i = 0; i < 16; ++i) woA[i] = W_out[oA * HH + l8 * 16 + i];
    const float boA = b_out[oA];

    // ---- pass-B constants: (tB, mB, qB) ----
    const int qB = tid & 3;
    const int mB = (tid >> 2) & 3;
    const int tB = tid >> 4;            // 0..31
    const float b2B = b_r2[qB & 1];

    // ---- init ----
    for (int idx = tid; idx < 2 * 512; idx += BLK) ((_Float16*)hp2)[idx] = (_Float16)0.0f;
    for (int idx = tid; idx < MM * SS * 2; idx += BLK) {
        const int m = idx >> 10, i = idx & 1023;          // i = t*2 + o
        v_lds[(i >> 1) * 8 + m * 2 + (i & 1)] = v_seq[(size_t)(row0 + m) * (SS * 2) + i];
    }
    if (tid < 64) {   // packed residual-MLP weights
        wpk[tid][0] = W_r1[tid*4];   wpk[tid][1] = W_r1[tid*4+1];
        wpk[tid][2] = W_r1[tid*4+2]; wpk[tid][3] = W_r1[tid*4+3];
        wpk[tid][4] = b_r1[tid];
        wpk[tid][5] = W_r2[tid];     wpk[tid][6] = W_r2[64 + tid];
        wpk[tid][7] = 0.0f;
    }
    if (tid < 8)
        xc[0][tid] = x0[(size_t)(row0 + (tid >> 1)) * 2 + (tid & 1)];
    __syncthreads();

    float hold = 0.0f;   // h[quad][j] in fp32 — the only recurrent state
    f32x2 vv2 = *(const f32x2*)&v_lds[quad * 2];   // prefetched v[t] (t=0)
    // pre-scaled x-projection terms (computed in barrier shadow)
    float vxr = fmaf(vv2[0], wr0, fmaf(vv2[1], wr1, brS));
    float vxz = fmaf(vv2[0], wz0, fmaf(vv2[1], wz1, bzS));
    float vxn = fmaf(vv2[0], wn0, fmaf(vv2[1], wn1, bniS));

    for (int t = 0; t < SS; ++t) {
        const int cur = t & 1, nxt = cur ^ 1;

        const _Float16* hb = &hp2[cur][rbase];
        const f16x8 af0 = *(const f16x8*)&hb[0 * 128];
        const f16x8 af1 = *(const f16x8*)&hb[1 * 128];
        const f16x8 af2 = *(const f16x8*)&hb[2 * 128];
        const f16x8 af3 = *(const f16x8*)&hb[3 * 128];

        // ---- gate 0 (r) MFMAs first; its trans ops overlap gate-1/2 MFMAs ----
        f32x4 aL0 = {0,0,0,0}, aG0 = {0,0,0,0};
        aL0 = __builtin_amdgcn_mfma_f32_16x16x32_f16(af0, whi[0][0], aL0, 0, 0, 0);
        aG0 = __builtin_amdgcn_mfma_f32_16x16x32_f16(af2, whi[0][2], aG0, 0, 0, 0);
        aL0 = __builtin_amdgcn_mfma_f32_16x16x32_f16(af1, whi[0][1], aL0, 0, 0, 0);
        aG0 = __builtin_amdgcn_mfma_f32_16x16x32_f16(af3, whi[0][3], aG0, 0, 0, 0);
        const float gh0 = aL0[0] + aG0[0];
        const float er  = exp2_fast(fmaf(gh0, -L2E, vxr));   // issues on trans pipe

        // ---- gate 1 (z) ----
        f32x4 aL1 = {0,0,0,0}, aG1 = {0,0,0,0};
        aL1 = __builtin_amdgcn_mfma_f32_16x16x32_f16(af0, whi[1][0], aL1, 0, 0, 0);
        aG1 = __builtin_amdgcn_mfma_f32_16x16x32_f16(af2, whi[1][2], aG1, 0, 0, 0);
        aL1 = __builtin_amdgcn_mfma_f32_16x16x32_f16(af1, whi[1][1], aL1, 0, 0, 0);
        aG1 = __builtin_amdgcn_mfma_f32_16x16x32_f16(af3, whi[1][3], aG1, 0, 0, 0);
        const float gh1 = aL1[0] + aG1[0];
        const float ez  = exp2_fast(fmaf(gh1, -L2E, vxz));
        const float r   = rcp_fast(1.0f + er);

        // ---- gate 2 (n) ----
        f32x4 aL2 = {0,0,0,0}, aG2 = {0,0,0,0};
        aL2 = __builtin_amdgcn_mfma_f32_16x16x32_f16(af0, whi[2][0], aL2, 0, 0, 0);
        aG2 = __builtin_amdgcn_mfma_f32_16x16x32_f16(af2, whi[2][2], aG2, 0, 0, 0);
        aL2 = __builtin_amdgcn_mfma_f32_16x16x32_f16(af1, whi[2][1], aL2, 0, 0, 0);
        aG2 = __builtin_amdgcn_mfma_f32_16x16x32_f16(af3, whi[2][3], aG2, 0, 0, 0);
        const float gh2 = aL2[0] + aG2[0];

        const float z   = rcp_fast(1.0f + ez);
        // arg_n = -2L2E*(vxn_raw + r*(gh2+bnh)) = vxn + r*fmaf(gh2,-2L2E,bnhS)
        const float en  = exp2_fast(fmaf(r, fmaf(gh2, -2.0f*L2E, bnhS), vxn));
        const float n   = fmaf(2.0f, rcp_fast(1.0f + en), -1.0f);
        hold = fmaf(z, hold - n, n);

        const _Float16 hh = (_Float16)hold;
        hp2[nxt][wbase] = hh;
        ring[((t & (RS-1)) * 4 + quad) * RStr + j] = hh;   // h_seq[t] for the epilogue

        // prefetch + precompute next step's pre-scaled x-projection (barrier shadow)
        vv2 = *(const f32x2*)&v_lds[((t + 1) & (SS - 1)) * 8 + quad * 2];
        vxr = fmaf(vv2[0], wr0, fmaf(vv2[1], wr1, brS));
        vxz = fmaf(vv2[0], wz0, fmaf(vv2[1], wz1, bzS));
        vxn = fmaf(vv2[0], wn0, fmaf(vv2[1], wn1, bniS));

        __syncthreads();

        // ---------- batched epilogue every RS steps ----------
        if ((t & (RS - 1)) == (RS - 1)) {
            const int f  = t >> 5;       // flush index
            const int t0 = t - (RS - 1);

            // pass A: x_pred for the window (8-lane dot groups, 4 passes)
            if (tid < 8) xs[0][tid] = xc[f & 1][tid];
#pragma unroll
            for (int p = 0; p < 4; ++p) {
                const int tt = p * 8 + tt8;
                const f16x8 h0 = *(const f16x8*)&ring[(tt * 4 + mA) * RStr + l8 * 16];
                const f16x8 h1 = *(const f16x8*)&ring[(tt * 4 + mA) * RStr + l8 * 16 + 8];
                float acc = 0.0f;
#pragma unroll
                for (int i = 0; i < 8; ++i) {
                    acc += (float)h0[i] * woA[i];
                    acc += (float)h1[i] * woA[8 + i];
                }
                acc += __shfl_xor(acc, 1, 64);
                acc += __shfl_xor(acc, 2, 64);
                acc += __shfl_xor(acc, 4, 64);
                if (l8 == 0) xs[1 + tt][mA * 2 + oA] = acc + boA;
            }
            __syncthreads();

            // pass B: residual MLP + violations + stores; thread = (tB, mB, qB)
            // u = uu*4 + qB: the 4 qB lanes read banks {0,8,16,24} -> conflict-free
            {
                const float xp0 = xs[tB][mB*2], xp1 = xs[tB][mB*2+1];
                const f32x2 vt2 = *(const f32x2*)&v_lds[(t0 + tB) * 8 + mB * 2];
                float rss0 = 0.0f, rss1 = 0.0f;
#pragma unroll
                for (int uu = 0; uu < 16; ++uu) {
                    const int u = uu * 4 + qB;
                    const f32x4 wA = *(const f32x4*)&wpk[u][0];
                    const f32x4 wB = *(const f32x4*)&wpk[u][4];
                    const float hu = fmaxf(wB[0] + wA[0]*xp0 + wA[1]*xp1 + wA[2]*vt2[0] + wA[3]*vt2[1], 0.0f);
                    rss0 += hu * wB[1];
                    rss1 += hu * wB[2];
                }
                rss0 += __shfl_xor(rss0, 1, 64);
                rss1 += __shfl_xor(rss1, 1, 64);
                rss0 += __shfl_xor(rss0, 2, 64);
                rss1 += __shfl_xor(rss1, 2, 64);
                if (qB < 2) {
                    const int o = qB;
                    const float xpred = xs[tB + 1][mB*2 + o];
                    const float xpv   = xs[tB][mB*2 + o];
                    const float vv    = v_lds[(t0 + tB) * 8 + mB*2 + o];
                    const float resid = (o ? rss1 : rss0) + b2B;
                    const float viol  = xpred - (xpv + vv + resid);
                    const size_t base = (size_t)(row0 + mB) * (SS * 2) + (t0 + tB) * 2 + o;
                    out[base] = xpred;
                    out[(size_t)BB * SS * 2 + base] = viol;
                }
                if (tid < 8) xc[(f + 1) & 1][tid] = xs[RS][tid];   // carry to next window
            }
            __syncthreads();
        }
    }
}

extern "C" void kernel_launch(void* const* d_in, const int* in_sizes, int n_in,
                              void* d_out, int out_size, void* d_ws, size_t ws_size,
                              hipStream_t stream) {
    pig_kernel<<<dim3(NBLK), dim3(BLK), 0, stream>>>(
        (const float*)d_in[0],  (const float*)d_in[1],  (const float*)d_in[2],
        (const float*)d_in[3],  (const float*)d_in[4],  (const float*)d_in[5],
        (const float*)d_in[6],  (const float*)d_in[7],  (const float*)d_in[8],
        (const float*)d_in[9],  (const float*)d_in[10], (const float*)d_in[11],
        (float*)d_out);
}